// Round 2
// baseline (3315.754 us; speedup 1.0000x reference)
//
#include <hip/hip_runtime.h>
#include <stdint.h>

// Problem constants
#define B_   8
#define N_   32768
#define C_   32
#define K_   22
#define CAT_ 40

typedef unsigned short u16;
typedef unsigned int   u32;

// ---------- bf16 helpers (raw bits) ----------
__device__ __forceinline__ float b2f(u16 v) { return __uint_as_float(((u32)v) << 16); }
__device__ __forceinline__ u16 f2b(float f) {
    u32 x = __float_as_uint(f);
    return (u16)((x + 0x7fffu + ((x >> 16) & 1u)) >> 16);   // RNE
}

// ---------- W8 (8-row-interleaved fp32 weights) offsets, in floats ----------
#define OFF_WIN 0        // 256x24
#define OFF_W1  6144     // 2 x 64x256
#define OFF_W2  38912    // 2 x 128x64
#define OFF_W3  55296    // 2 x 128x128
#define OFF_WC1 88064    // 2 x 128x128
#define OFF_WC2 120832   // 2 x 256x128
#define OFF_WC3 186368   // 2 x 32x256
#define OFF_WO1 202752   // 128x256
#define OFF_WO2 235520   // 128x128
// total 251904 floats < 1 MB

// ---------- fp32 bias block offsets (floats) ----------
#define OBIN 0
#define OB1  256
#define OB2  384
#define OB3  640
#define OBC1 896
#define OBC2 1152
#define OBC3 1664
#define OBO1 1728
#define OBO2 1856
#define ODB1 1984
#define ODB2 2240
#define ODB3 2496
// total 2536 floats

// ---------- canonical bf16 dense-head weights (u16 offsets) ----------
#define ODW1 0
#define ODW2 32768
#define ODW3 98304
// total 108544 u16

// ---------- workspace byte offsets ----------
#define OFS_BIAS  1048576u
#define OFS_DWC   1114112u
#define OFS_MODE  1376256u
#define OFS_FEATC 1441792u     // 5,767,168 u16 = 11,534,336 B
#define OFS_GACC0 13107200u
#define OFS_GACC1 13271040u
#define OFS_GNET  13434880u
#define GACC_ZERO_BYTES 331776u   // gacc0+gacc1+gnet contiguous
#define OFS_CF20  13438976u
#define OFS_CF21  13570048u
#define OFS_F0    16777216u
#define OFS_F1    83886080u
// end = 150,994,944 bytes (~144 MB)

// ---------- dtype sniffer: decide if float tensors are fp32 (mode=1) or bf16 (mode=0) ----------
// True-bf16 N(0,1) data: decoded values are finite, moderate, never exactly 0x0000.
// fp32 data (raw or bf16-quantized-upcast): half the u16 elements are mantissa
// low-halves -> exact zeros or huge/NaN bf16 patterns.
__global__ void kSniff(const u16* __restrict__ featAny, int* __restrict__ mode) {
    __shared__ int cnt;
    if (threadIdx.x == 0) cnt = 0;
    __syncthreads();
    int weird = 0;
    for (int j = 0; j < 4; ++j) {
        u16 v = featAny[threadIdx.x * 4 + j];
        float f = b2f(v);
        if (v == 0 || !(fabsf(f) < 1e10f)) weird++;   // catches 0x0000, inf, NaN, garbage
    }
    if (weird) atomicAdd(&cnt, weird);
    __syncthreads();
    if (threadIdx.x == 0) *mode = (cnt > 64) ? 1 : 0;
}

// ---------- dual-mode element fetch ----------
__device__ __forceinline__ float fetchF(const void* src, size_t i, int mode) {
    return mode ? ((const float*)src)[i] : b2f(((const u16*)src)[i]);
}

// ---------- weight prep: (COUT,CIN) -> fp32 [COUT/8][CINL][8] ----------
__device__ void cvtW8(const void* __restrict__ src, float* __restrict__ dst,
                      int COUT, int CIN, int CINL, int mode, int tid, int np) {
    int tot = COUT * CINL;
    for (int i = tid; i < tot; i += np) {
        int u = i & 7;
        int r = i >> 3;
        int ci = r % CINL;
        int g  = r / CINL;
        int co = g * 8 + u;
        dst[i] = (ci < CIN) ? fetchF(src, (size_t)co * CIN + ci, mode) : 0.f;
    }
}

__device__ void cvtF(const void* __restrict__ src, float* __restrict__ dst,
                     int n, int mode, int tid, int np) {
    for (int i = tid; i < n; i += np) dst[i] = fetchF(src, i, mode);
}

__device__ void cvtB(const void* __restrict__ src, u16* __restrict__ dst,
                     int n, int mode, int tid, int np) {
    for (int i = tid; i < n; i += np)
        dst[i] = mode ? f2b(((const float*)src)[i]) : ((const u16*)src)[i];
}

__global__ void kPrep(const void* feat, const void* w_in, const void* b_in,
                      const void* w1, const void* b1, const void* w2, const void* b2,
                      const void* w3, const void* b3,
                      const void* wc1, const void* bc1, const void* wc2, const void* bc2,
                      const void* wc3, const void* bc3,
                      const void* wo1, const void* bo1, const void* wo2, const void* bo2,
                      const void* dw1, const void* db1, const void* dw2, const void* db2,
                      const void* dw3, const void* db3,
                      float* W8, float* BIAS, u16* DWC, u16* FEATC,
                      const int* __restrict__ modep) {
    const int mode = *modep;
    int tid = blockIdx.x * blockDim.x + threadIdx.x;
    int np  = gridDim.x * blockDim.x;
    // feature canon (the big one)
    cvtB(feat, FEATC, B_ * N_ * K_, mode, tid, np);
    // weight canon
    cvtW8(w_in, W8 + OFF_WIN, 256, 22, 24, mode, tid, np);
    cvtW8((const char*)w1 + 0,              W8 + OFF_W1,          64, 256, 256, mode, tid, np);
    cvtW8((const u16*)w1 + (mode?32768:16384), W8 + OFF_W1 + 16384, 64, 256, 256, mode, tid, np);
    cvtW8((const char*)w2 + 0,              W8 + OFF_W2,          128, 64, 64, mode, tid, np);
    cvtW8((const u16*)w2 + (mode?16384:8192),  W8 + OFF_W2 + 8192,  128, 64, 64, mode, tid, np);
    cvtW8((const char*)w3 + 0,              W8 + OFF_W3,          128, 128, 128, mode, tid, np);
    cvtW8((const u16*)w3 + (mode?32768:16384), W8 + OFF_W3 + 16384, 128, 128, 128, mode, tid, np);
    cvtW8((const char*)wc1 + 0,             W8 + OFF_WC1,         128, 128, 128, mode, tid, np);
    cvtW8((const u16*)wc1 + (mode?32768:16384), W8 + OFF_WC1 + 16384, 128, 128, 128, mode, tid, np);
    cvtW8((const char*)wc2 + 0,             W8 + OFF_WC2,         256, 128, 128, mode, tid, np);
    cvtW8((const u16*)wc2 + (mode?65536:32768), W8 + OFF_WC2 + 32768, 256, 128, 128, mode, tid, np);
    cvtW8((const char*)wc3 + 0,             W8 + OFF_WC3,         32, 256, 256, mode, tid, np);
    cvtW8((const u16*)wc3 + (mode?16384:8192),  W8 + OFF_WC3 + 8192, 32, 256, 256, mode, tid, np);
    cvtW8(wo1, W8 + OFF_WO1, 128, 256, 256, mode, tid, np);
    cvtW8(wo2, W8 + OFF_WO2, 128, 128, 128, mode, tid, np);
    // biases -> fp32
    cvtF(b_in, BIAS + OBIN, 256, mode, tid, np);
    cvtF(b1,   BIAS + OB1,  128, mode, tid, np);
    cvtF(b2,   BIAS + OB2,  256, mode, tid, np);
    cvtF(b3,   BIAS + OB3,  256, mode, tid, np);
    cvtF(bc1,  BIAS + OBC1, 256, mode, tid, np);
    cvtF(bc2,  BIAS + OBC2, 512, mode, tid, np);
    cvtF(bc3,  BIAS + OBC3, 64,  mode, tid, np);
    cvtF(bo1,  BIAS + OBO1, 128, mode, tid, np);
    cvtF(bo2,  BIAS + OBO2, 128, mode, tid, np);
    cvtF(db1,  BIAS + ODB1, 256, mode, tid, np);
    cvtF(db2,  BIAS + ODB2, 256, mode, tid, np);
    cvtF(db3,  BIAS + ODB3, 40,  mode, tid, np);
    // dense-head weights -> bf16 canon
    cvtB(dw1, DWC + ODW1, 128 * 256, mode, tid, np);
    cvtB(dw2, DWC + ODW2, 256 * 256, mode, tid, np);
    cvtB(dw3, DWC + ODW3, 256 * 40,  mode, tid, np);
}

// ---------- generic producer conv: LDS bf16 in -> LDS bf16 out (ReLU) ----------
template<int COUT, int CINL, int INS, int OUTS, bool NETMAX = false>
__device__ __forceinline__ void conv_full(const float* __restrict__ w8,
                                          const float* __restrict__ bias, int coBase,
                                          const u16* __restrict__ sIn,
                                          u16* __restrict__ sOut, int* sNet) {
    const int t  = threadIdx.x;
    const int pt = t & 63;
    const int wv = __builtin_amdgcn_readfirstlane(t >> 6);
    constexpr int CPW = COUT / 4;
    for (int j0 = 0; j0 < CPW; j0 += 8) {
        const int co = coBase + wv * CPW + j0;
        const float* wp = w8 + (size_t)(co >> 3) * (CINL * 8);
        float acc[8];
#pragma unroll
        for (int u = 0; u < 8; ++u) acc[u] = bias[co + u];
#pragma unroll 2
        for (int ci = 0; ci < CINL; ci += 8) {
            uint4 raw = *(const uint4*)(sIn + pt * INS + ci);
            float a[8];
            a[0] = b2f((u16)raw.x); a[1] = b2f((u16)(raw.x >> 16));
            a[2] = b2f((u16)raw.y); a[3] = b2f((u16)(raw.y >> 16));
            a[4] = b2f((u16)raw.z); a[5] = b2f((u16)(raw.z >> 16));
            a[6] = b2f((u16)raw.w); a[7] = b2f((u16)(raw.w >> 16));
#pragma unroll
            for (int j = 0; j < 8; ++j) {
                const float* wr = wp + (size_t)(ci + j) * 8;
#pragma unroll
                for (int u = 0; u < 8; ++u) acc[u] = fmaf(wr[u], a[j], acc[u]);
            }
        }
        if constexpr (NETMAX) {
            const int cl = wv * CPW + j0;
#pragma unroll
            for (int u = 0; u < 8; ++u)
                atomicMax(&sNet[cl + u], __float_as_int(fmaxf(acc[u], 0.f)));
        } else {
            const int oc = wv * CPW + j0;
            u32 q[4];
#pragma unroll
            for (int u = 0; u < 8; u += 2) {
                q[u / 2] = (u32)f2b(fmaxf(acc[u], 0.f)) |
                           ((u32)f2b(fmaxf(acc[u + 1], 0.f)) << 16);
            }
            *(uint4*)(sOut + pt * OUTS + oc) = make_uint4(q[0], q[1], q[2], q[3]);
        }
    }
}

// ---------- chunk consumer: accumulate JPW out-channels per thread from a 32-ch chunk ----------
template<int JPW>
__device__ __forceinline__ void consume_chunk(const float* __restrict__ w8,
                                              int cbase, const u16* __restrict__ sCh,
                                              float* acc) {
    const int t  = threadIdx.x;
    const int pt = t & 63;
    const int g0 = __builtin_amdgcn_readfirstlane((t >> 6) * (JPW / 8));
    for (int mb = 0; mb < 32; mb += 8) {
        uint4 raw = *(const uint4*)(sCh + pt * 40 + mb);
        float a[8];
        a[0] = b2f((u16)raw.x); a[1] = b2f((u16)(raw.x >> 16));
        a[2] = b2f((u16)raw.y); a[3] = b2f((u16)(raw.y >> 16));
        a[4] = b2f((u16)raw.z); a[5] = b2f((u16)(raw.z >> 16));
        a[6] = b2f((u16)raw.w); a[7] = b2f((u16)(raw.w >> 16));
#pragma unroll
        for (int gg = 0; gg < JPW / 8; ++gg) {
            const float* wp = w8 + ((size_t)(g0 + gg) * 256 + cbase + mb) * 8;
#pragma unroll
            for (int m = 0; m < 8; ++m)
#pragma unroll
                for (int u = 0; u < 8; ++u)
                    acc[gg * 8 + u] = fmaf(wp[m * 8 + u], a[m], acc[gg * 8 + u]);
        }
    }
}

// ---------- iteration-0 fused kernel ----------
__global__ __launch_bounds__(256)
void kA0(const u16* __restrict__ featc, const int* __restrict__ clu0,
         const float* __restrict__ win8, const float* __restrict__ w18,
         const float* __restrict__ w28, const float* __restrict__ wc18,
         const float* __restrict__ wc28, const float* __restrict__ wc38,
         const float* bin, const float* b1p, const float* b2p,
         const float* bc1p, const float* bc2p, const float* bc3p,
         u32* __restrict__ gF, int* __restrict__ gSeg) {
    __shared__ __attribute__((aligned(16))) u16 sF[64 * 136];
    __shared__ __attribute__((aligned(16))) u16 sH[64 * 136];
    __shared__ __attribute__((aligned(16))) u16 sCh[64 * 40];
    __shared__ int sSeg[32 * 160];
    __shared__ int sClu[64];
    const int t = threadIdx.x;
    const int b = blockIdx.y;
    const size_t bN = (size_t)b * N_;
    for (int i = t; i < 5120; i += 256) sSeg[i] = 0;

    for (int s = 0; s < 8; ++s) {
        const int n0 = blockIdx.x * 512 + s * 64;
        for (int i = t; i < 64 * 24; i += 256) {
            int pt = i / 24, k = i - pt * 24;
            sH[pt * 136 + k] = (k < 22) ? featc[(bN + n0 + pt) * 22 + k] : (u16)0;
        }
        if (t < 64) sClu[t] = clu0[bN + n0 + t];
        __syncthreads();
        float hacc[16];
        { const int jb = (t >> 6) * 16;
#pragma unroll
          for (int u = 0; u < 16; ++u) hacc[u] = b1p[jb + u]; }
        for (int c = 0; c < 8; ++c) {
            conv_full<32, 24, 136, 40>(win8, bin, c * 32, sH, sCh, nullptr);
            __syncthreads();
            consume_chunk<16>(w18, c * 32, sCh, hacc);
            __syncthreads();
        }
        { const int pt = t & 63, jb = (t >> 6) * 16;
#pragma unroll
          for (int u = 0; u < 16; u += 2) {
              u32 v = (u32)f2b(fmaxf(hacc[u], 0.f)) |
                      ((u32)f2b(fmaxf(hacc[u + 1], 0.f)) << 16);
              *(u32*)(sH + pt * 136 + jb + u) = v;
          } }
        __syncthreads();
        conv_full<128, 64, 136, 136>(w28, b2p, 0, sH, sF, nullptr);   // f128
        __syncthreads();
        for (int i = t; i < 8192; i += 256) {
            int pt = i >> 7, ch = i & 127;
            atomicMax(&sSeg[sClu[pt] * 160 + ch],
                      __float_as_int(b2f(sF[pt * 136 + ch])));
        }
        for (int i = t; i < 4096; i += 256) {
            int pt = i >> 6, c2 = i & 63;
            u32 v = (u32)sF[pt * 136 + c2 * 2] | ((u32)sF[pt * 136 + c2 * 2 + 1] << 16);
            gF[(bN + n0 + pt) * 64 + c2] = v;
        }
        conv_full<128, 128, 136, 136>(wc18, bc1p, 0, sF, sH, nullptr);
        __syncthreads();
        float cacc[8];
        { const int jb = (t >> 6) * 8;
#pragma unroll
          for (int u = 0; u < 8; ++u) cacc[u] = bc3p[jb + u]; }
        for (int c = 0; c < 8; ++c) {
            conv_full<32, 128, 136, 40>(wc28, bc2p, c * 32, sH, sCh, nullptr);
            __syncthreads();
            consume_chunk<8>(wc38, c * 32, sCh, cacc);
            __syncthreads();
        }
        { const int pt = t & 63, jb = (t >> 6) * 8;
          const int c = sClu[pt];
#pragma unroll
          for (int u = 0; u < 8; ++u)
              atomicMax(&sSeg[c * 160 + 128 + jb + u],
                        __float_as_int(fmaxf(cacc[u], 0.f)));
        }
        __syncthreads();
    }
    for (int i = t; i < 5120; i += 256) atomicMax(&gSeg[b * 5120 + i], sSeg[i]);
}

// ---------- per-batch cluster math: cf2[b][c][ch] ----------
__global__ __launch_bounds__(256)
void kB(const int* __restrict__ gSeg, float* __restrict__ cf2) {
    __shared__ float sA[5120];
    __shared__ float sR[1024];
    __shared__ float sI[32];
    const int t = threadIdx.x, b = blockIdx.x;
    for (int i = t; i < 5120; i += 256) sA[i] = __int_as_float(gSeg[b * 5120 + i]);
    __syncthreads();
    if (t < 32) {
        float s = 0.f;
        for (int j = 0; j < 32; ++j) { float v = sA[t * 160 + 128 + j]; s = fmaf(v, v, s); }
        sI[t] = 1.f / fmaxf(sqrtf(s), 1e-12f);
    }
    __syncthreads();
    for (int i = t; i < 1024; i += 256) {
        int ca = i >> 5, cb = i & 31;
        float s = 0.f;
        for (int j = 0; j < 32; ++j)
            s = fmaf(sA[ca * 160 + 128 + j], sA[cb * 160 + 128 + j], s);
        sR[i] = s * sI[ca] * sI[cb];
    }
    __syncthreads();
    for (int i = t; i < 4096; i += 256) {
        int c = i >> 7, ch = i & 127;
        float s = 0.f;
        for (int cp = 0; cp < 32; ++cp)
            s = fmaf(sA[cp * 160 + ch], sR[cp * 32 + c], s);
        cf2[((size_t)b * 32 + c) * 128 + ch] = s;
    }
}

// ---------- iteration-1 fused kernel ----------
__global__ __launch_bounds__(256)
void kA1(const u32* __restrict__ gFp, const int* __restrict__ clu_g,
         const int* __restrict__ clu_s, const float* __restrict__ cf2,
         const float* __restrict__ w38, const float* __restrict__ w18,
         const float* __restrict__ w28, const float* __restrict__ wc18,
         const float* __restrict__ wc28, const float* __restrict__ wc38,
         const float* b3p, const float* b1p, const float* b2p,
         const float* bc1p, const float* bc2p, const float* bc3p,
         u32* __restrict__ gFo, int* __restrict__ gSeg) {
    __shared__ __attribute__((aligned(16))) u16 sF[64 * 136];
    __shared__ __attribute__((aligned(16))) u16 sH[64 * 136];
    __shared__ __attribute__((aligned(16))) u16 sCh[64 * 40];
    __shared__ int sSeg[32 * 160];
    __shared__ int sClu0[64];
    __shared__ int sClu1[64];
    const int t = threadIdx.x;
    const int b = blockIdx.y;
    const size_t bN = (size_t)b * N_;
    for (int i = t; i < 5120; i += 256) sSeg[i] = 0;

    for (int s = 0; s < 8; ++s) {
        const int n0 = blockIdx.x * 512 + s * 64;
        for (int i = t; i < 4096; i += 256) {
            int pt = i >> 6, c2 = i & 63;
            u32 v = gFp[(bN + n0 + pt) * 64 + c2];
            sF[pt * 136 + c2 * 2] = (u16)v;
            sF[pt * 136 + c2 * 2 + 1] = (u16)(v >> 16);
        }
        if (t < 64) sClu0[t] = clu_g[bN + n0 + t];
        else if (t < 128) sClu1[t - 64] = clu_s[bN + n0 + (t - 64)];
        __syncthreads();
        float hacc[16];
        { const int jb = (t >> 6) * 16;
#pragma unroll
          for (int u = 0; u < 16; ++u) hacc[u] = b1p[jb + u]; }
        for (int c = 0; c < 8; ++c) {
            if (c < 4) {
                conv_full<32, 128, 136, 40>(w38, b3p, c * 32, sF, sCh, nullptr);
            } else {
                for (int i = t; i < 2048; i += 256) {
                    int pt = i >> 5, m = i & 31;
                    sCh[pt * 40 + m] =
                        f2b(cf2[((size_t)b * 32 + sClu0[pt]) * 128 + (c - 4) * 32 + m]);
                }
            }
            __syncthreads();
            consume_chunk<16>(w18, c * 32, sCh, hacc);
            __syncthreads();
        }
        { const int pt = t & 63, jb = (t >> 6) * 16;
#pragma unroll
          for (int u = 0; u < 16; u += 2) {
              u32 v = (u32)f2b(fmaxf(hacc[u], 0.f)) |
                      ((u32)f2b(fmaxf(hacc[u + 1], 0.f)) << 16);
              *(u32*)(sH + pt * 136 + jb + u) = v;
          } }
        __syncthreads();
        conv_full<128, 64, 136, 136>(w28, b2p, 0, sH, sF, nullptr);   // f128_1
        __syncthreads();
        for (int i = t; i < 8192; i += 256) {
            int pt = i >> 7, ch = i & 127;
            atomicMax(&sSeg[sClu1[pt] * 160 + ch],
                      __float_as_int(b2f(sF[pt * 136 + ch])));
        }
        for (int i = t; i < 4096; i += 256) {
            int pt = i >> 6, c2 = i & 63;
            u32 v = (u32)sF[pt * 136 + c2 * 2] | ((u32)sF[pt * 136 + c2 * 2 + 1] << 16);
            gFo[(bN + n0 + pt) * 64 + c2] = v;
        }
        conv_full<128, 128, 136, 136>(wc18, bc1p, 0, sF, sH, nullptr);
        __syncthreads();
        float cacc[8];
        { const int jb = (t >> 6) * 8;
#pragma unroll
          for (int u = 0; u < 8; ++u) cacc[u] = bc3p[jb + u]; }
        for (int c = 0; c < 8; ++c) {
            conv_full<32, 128, 136, 40>(wc28, bc2p, c * 32, sH, sCh, nullptr);
            __syncthreads();
            consume_chunk<8>(wc38, c * 32, sCh, cacc);
            __syncthreads();
        }
        { const int pt = t & 63, jb = (t >> 6) * 8;
          const int c = sClu1[pt];
#pragma unroll
          for (int u = 0; u < 8; ++u)
              atomicMax(&sSeg[c * 160 + 128 + jb + u],
                        __float_as_int(fmaxf(cacc[u], 0.f)));
        }
        __syncthreads();
    }
    for (int i = t; i < 5120; i += 256) atomicMax(&gSeg[b * 5120 + i], sSeg[i]);
}

// ---------- final conv head + per-channel max over points ----------
__global__ __launch_bounds__(256)
void kC(const u32* __restrict__ gFp, const int* __restrict__ clu_g,
        const float* __restrict__ cf2,
        const float* __restrict__ w38, const float* __restrict__ wo18,
        const float* __restrict__ wo28,
        const float* b3p, const float* bo1, const float* bo2,
        int* __restrict__ gNet) {
    __shared__ __attribute__((aligned(16))) u16 sF[64 * 136];
    __shared__ __attribute__((aligned(16))) u16 sH[64 * 136];
    __shared__ __attribute__((aligned(16))) u16 sCh[64 * 40];
    __shared__ int sNet[128];
    __shared__ int sClu[64];
    const int t = threadIdx.x;
    const int b = blockIdx.y;
    const size_t bN = (size_t)b * N_;
    if (t < 128) sNet[t] = 0;

    for (int s = 0; s < 8; ++s) {
        const int n0 = blockIdx.x * 512 + s * 64;
        for (int i = t; i < 4096; i += 256) {
            int pt = i >> 6, c2 = i & 63;
            u32 v = gFp[(bN + n0 + pt) * 64 + c2];
            sF[pt * 136 + c2 * 2] = (u16)v;
            sF[pt * 136 + c2 * 2 + 1] = (u16)(v >> 16);
        }
        if (t < 64) sClu[t] = clu_g[bN + n0 + t];
        __syncthreads();
        float oacc[32];
        { const int jb = (t >> 6) * 32;
#pragma unroll
          for (int u = 0; u < 32; ++u) oacc[u] = bo1[jb + u]; }
        for (int c = 0; c < 8; ++c) {
            if (c < 4) {
                conv_full<32, 128, 136, 40>(w38, b3p, c * 32, sF, sCh, nullptr);
            } else {
                for (int i = t; i < 2048; i += 256) {
                    int pt = i >> 5, m = i & 31;
                    sCh[pt * 40 + m] =
                        f2b(cf2[((size_t)b * 32 + sClu[pt]) * 128 + (c - 4) * 32 + m]);
                }
            }
            __syncthreads();
            consume_chunk<32>(wo18, c * 32, sCh, oacc);
            __syncthreads();
        }
        { const int pt = t & 63, jb = (t >> 6) * 32;
#pragma unroll
          for (int u = 0; u < 32; u += 2) {
              u32 v = (u32)f2b(fmaxf(oacc[u], 0.f)) |
                      ((u32)f2b(fmaxf(oacc[u + 1], 0.f)) << 16);
              *(u32*)(sH + pt * 136 + jb + u) = v;
          } }
        __syncthreads();
        conv_full<128, 128, 136, 136, true>(wo28, bo2, 0, sH, nullptr, sNet);
        __syncthreads();
    }
    if (t < 128) atomicMax(&gNet[b * 128 + t], sNet[t]);
}

// ---------- tiny MLP head (dual-mode output) ----------
__global__ __launch_bounds__(256)
void kD(const int* __restrict__ gNet, const u16* __restrict__ DWC,
        const float* __restrict__ BIAS, void* __restrict__ outv,
        const int* __restrict__ modep) {
    __shared__ float sN[1024];
    __shared__ float sD1[2048];
    __shared__ float sD2[2048];
    const int mode = *modep;
    const int t = threadIdx.x;
    for (int i = t; i < 1024; i += 256) sN[i] = __int_as_float(gNet[i]);
    __syncthreads();
    for (int i = t; i < 2048; i += 256) {
        int bb = i >> 8, o = i & 255;
        float s = BIAS[ODB1 + o];
        for (int k = 0; k < 128; ++k)
            s = fmaf(sN[bb * 128 + k], b2f(DWC[ODW1 + k * 256 + o]), s);
        sD1[i] = (s >= 0.f) ? s : 0.2f * s;
    }
    __syncthreads();
    for (int i = t; i < 2048; i += 256) {
        int bb = i >> 8, o = i & 255;
        float s = BIAS[ODB2 + o];
        for (int k = 0; k < 256; ++k)
            s = fmaf(sD1[bb * 256 + k], b2f(DWC[ODW2 + k * 256 + o]), s);
        sD2[i] = (s >= 0.f) ? s : 0.2f * s;
    }
    __syncthreads();
    for (int i = t; i < 320; i += 256) {
        int bb = i / 40, o = i - bb * 40;
        float s = BIAS[ODB3 + o];
        for (int k = 0; k < 256; ++k)
            s = fmaf(sD2[bb * 256 + k], b2f(DWC[ODW3 + k * 40 + o]), s);
        if (mode) ((float*)outv)[i] = s;
        else      ((u16*)outv)[i]   = f2b(s);
    }
}

extern "C" void kernel_launch(void* const* d_in, const int* in_sizes, int n_in,
                              void* d_out, int out_size, void* d_ws, size_t ws_size,
                              hipStream_t stream) {
    const void* feat = d_in[0];
    const int* clus = (const int*)d_in[1];

    char* ws = (char*)d_ws;
    float* W8    = (float*)(ws);
    float* BIAS  = (float*)(ws + OFS_BIAS);
    u16*   DWC   = (u16*)(ws + OFS_DWC);
    int*   modep = (int*)(ws + OFS_MODE);
    u16*   FEATC = (u16*)(ws + OFS_FEATC);
    int*   seg0  = (int*)(ws + OFS_GACC0);
    int*   seg1  = (int*)(ws + OFS_GACC1);
    int*   gNet  = (int*)(ws + OFS_GNET);
    float* cf20  = (float*)(ws + OFS_CF20);
    float* cf21  = (float*)(ws + OFS_CF21);
    u32*   f0    = (u32*)(ws + OFS_F0);
    u32*   f1    = (u32*)(ws + OFS_F1);

    hipMemsetAsync(ws + OFS_GACC0, 0, GACC_ZERO_BYTES, stream);
    hipLaunchKernelGGL(kSniff, dim3(1), dim3(256), 0, stream, (const u16*)feat, modep);
    hipLaunchKernelGGL(kPrep, dim3(256), dim3(256), 0, stream,
                       feat, d_in[2], d_in[3], d_in[4], d_in[5], d_in[6], d_in[7],
                       d_in[8], d_in[9], d_in[10], d_in[11], d_in[12], d_in[13],
                       d_in[14], d_in[15], d_in[16], d_in[17], d_in[18], d_in[19],
                       d_in[20], d_in[21], d_in[22], d_in[23], d_in[24], d_in[25],
                       W8, BIAS, DWC, FEATC, modep);

    dim3 grid(64, 8), blk(256);
    const int* clu0 = clus;
    const int* clu1 = clus + (size_t)B_ * N_;

    hipLaunchKernelGGL(kA0, grid, blk, 0, stream,
                       FEATC, clu0,
                       W8 + OFF_WIN, W8 + OFF_W1, W8 + OFF_W2,
                       W8 + OFF_WC1, W8 + OFF_WC2, W8 + OFF_WC3,
                       BIAS + OBIN, BIAS + OB1, BIAS + OB2,
                       BIAS + OBC1, BIAS + OBC2, BIAS + OBC3,
                       f0, seg0);
    hipLaunchKernelGGL(kB, dim3(8), blk, 0, stream, seg0, cf20);
    hipLaunchKernelGGL(kA1, grid, blk, 0, stream,
                       f0, clu0, clu1, cf20,
                       W8 + OFF_W3, W8 + OFF_W1 + 16384, W8 + OFF_W2 + 8192,
                       W8 + OFF_WC1 + 16384, W8 + OFF_WC2 + 32768, W8 + OFF_WC3 + 8192,
                       BIAS + OB3, BIAS + OB1 + 64, BIAS + OB2 + 128,
                       BIAS + OBC1 + 128, BIAS + OBC2 + 256, BIAS + OBC3 + 32,
                       f1, seg1);
    hipLaunchKernelGGL(kB, dim3(8), blk, 0, stream, seg1, cf21);
    hipLaunchKernelGGL(kC, grid, blk, 0, stream,
                       f1, clu1, cf21,
                       W8 + OFF_W3 + 16384, W8 + OFF_WO1, W8 + OFF_WO2,
                       BIAS + OB3 + 128, BIAS + OBO1, BIAS + OBO2, gNet);
    hipLaunchKernelGGL(kD, dim3(1), blk, 0, stream,
                       gNet, DWC, BIAS, d_out, modep);
}

// Round 3
// 740.849 us; speedup vs baseline: 4.4756x; 4.4756x over previous
//
#include <hip/hip_runtime.h>
#include <stdint.h>

// Problem constants
#define B_   8
#define N_   32768
#define C_   32
#define K_   22
#define CAT_ 40

typedef unsigned short u16;
typedef unsigned int   u32;

typedef __attribute__((ext_vector_type(8))) short bf16x8;
typedef __attribute__((ext_vector_type(4))) float f32x4;

#define MFMA(a, b, c) __builtin_amdgcn_mfma_f32_16x16x32_bf16(a, b, c, 0, 0, 0)

// ---------- bf16 helpers (raw bits) ----------
__device__ __forceinline__ float b2f(u16 v) { return __uint_as_float(((u32)v) << 16); }
__device__ __forceinline__ u16 f2b(float f) {
    u32 x = __float_as_uint(f);
    return (u16)((x + 0x7fffu + ((x >> 16) & 1u)) >> 16);   // RNE
}
__device__ __forceinline__ u32 pk2(float a, float b) {
    return (u32)f2b(a) | ((u32)f2b(b) << 16);
}

// ---------- packed MFMA A-fragment weight offsets (u16 units) ----------
// layout: idx = ((tile*KB + kb)*64 + lane)*8 + j ; element = W[tile*16 + (lane&15)][kb*32 + (lane>>4)*8 + j]
#define PK_WIN 0         // 256x32(pad), KB=1 : 8192
#define PK_W1  8192      // 2 x 64x256, KB=8  : 16384 each
#define PK_W2  40960     // 2 x 128x64, KB=2  : 8192 each
#define PK_W3  57344     // 2 x 128x128, KB=4 : 16384 each
#define PK_WC1 90112     // 2 x 128x128       : 16384 each
#define PK_WC2 122880    // 2 x 256x128, KB=4 : 32768 each
#define PK_WC3 188416    // 2 x 32x256, KB=8  : 8192 each
#define PK_WO1 204800    // 128x256, KB=8     : 32768
#define PK_WO2 237568    // 128x128, KB=4     : 16384
// total 253952 u16 = 507904 B

// ---------- fp32 bias block offsets (floats) ----------
#define OBIN 0
#define OB1  256
#define OB2  384
#define OB3  640
#define OBC1 896
#define OBC2 1152
#define OBC3 1664
#define OBO1 1728
#define OBO2 1856
#define ODB1 1984
#define ODB2 2240
#define ODB3 2496

// ---------- canonical bf16 dense-head weights (u16 offsets) ----------
#define ODW1 0
#define ODW2 32768
#define ODW3 98304

// ---------- workspace byte offsets ----------
#define OFS_WPK   0u
#define OFS_BIAS  524288u
#define OFS_DWC   540672u
#define OFS_MODE  786432u
#define OFS_FEATC 1048576u      // 5,767,168 u16 = 11,534,336 B
#define OFS_GACC0 12582912u
#define OFS_GACC1 12746752u
#define OFS_GNET  12910592u
#define GACC_ZERO_BYTES 331776u // gacc0+gacc1+gnet contiguous
#define OFS_CF20  12914688u
#define OFS_CF21  13045760u
#define OFS_F0    16777216u
#define OFS_F1    83886080u
// end = 150,994,944 bytes (~144 MB)

// ---------- dtype sniffer ----------
__global__ void kSniff(const u16* __restrict__ featAny, int* __restrict__ mode) {
    __shared__ int cnt;
    if (threadIdx.x == 0) cnt = 0;
    __syncthreads();
    int weird = 0;
    for (int j = 0; j < 4; ++j) {
        u16 v = featAny[threadIdx.x * 4 + j];
        float f = b2f(v);
        if (v == 0 || !(fabsf(f) < 1e10f)) weird++;
    }
    if (weird) atomicAdd(&cnt, weird);
    __syncthreads();
    if (threadIdx.x == 0) *mode = (cnt > 64) ? 1 : 0;
}

__device__ __forceinline__ float fetchF(const void* src, size_t i, int mode) {
    return mode ? ((const float*)src)[i] : b2f(((const u16*)src)[i]);
}

// ---------- weight pack: (COUT,CIN) -> MFMA A-fragment bf16 order ----------
__device__ void packA(const void* __restrict__ src, u16* __restrict__ dst,
                      int COUT, int CIN, int mode, int tid, int np) {
    int KB = (CIN + 31) / 32;
    int tiles = COUT / 16;
    int tot = tiles * KB * 64 * 8;
    for (int i = tid; i < tot; i += np) {
        int j = i & 7;
        int L = (i >> 3) & 63;
        int rest = i >> 9;
        int kb = rest % KB, tile = rest / KB;
        int co = tile * 16 + (L & 15);
        int ci = kb * 32 + (L >> 4) * 8 + j;
        float v = (ci < CIN) ? fetchF(src, (size_t)co * CIN + ci, mode) : 0.f;
        dst[i] = f2b(v);
    }
}

__device__ void cvtF(const void* __restrict__ src, float* __restrict__ dst,
                     int n, int mode, int tid, int np) {
    for (int i = tid; i < n; i += np) dst[i] = fetchF(src, i, mode);
}

__device__ void cvtB(const void* __restrict__ src, u16* __restrict__ dst,
                     int n, int mode, int tid, int np) {
    for (int i = tid; i < n; i += np)
        dst[i] = mode ? f2b(((const float*)src)[i]) : ((const u16*)src)[i];
}

__global__ void kPrep(const void* feat, const void* w_in, const void* b_in,
                      const void* w1, const void* b1, const void* w2, const void* b2,
                      const void* w3, const void* b3,
                      const void* wc1, const void* bc1, const void* wc2, const void* bc2,
                      const void* wc3, const void* bc3,
                      const void* wo1, const void* bo1, const void* wo2, const void* bo2,
                      const void* dw1, const void* db1, const void* dw2, const void* db2,
                      const void* dw3, const void* db3,
                      u16* WPK, float* BIAS, u16* DWC, u16* FEATC,
                      const int* __restrict__ modep) {
    const int mode = *modep;
    int tid = blockIdx.x * blockDim.x + threadIdx.x;
    int np  = gridDim.x * blockDim.x;
    cvtB(feat, FEATC, B_ * N_ * K_, mode, tid, np);
    packA(w_in, WPK + PK_WIN, 256, 22, mode, tid, np);
    packA(w1,                                 WPK + PK_W1,          64, 256, mode, tid, np);
    packA((const u16*)w1 + (mode?32768:16384), WPK + PK_W1 + 16384,  64, 256, mode, tid, np);
    packA(w2,                                 WPK + PK_W2,          128, 64, mode, tid, np);
    packA((const u16*)w2 + (mode?16384:8192),  WPK + PK_W2 + 8192,   128, 64, mode, tid, np);
    packA(w3,                                 WPK + PK_W3,          128, 128, mode, tid, np);
    packA((const u16*)w3 + (mode?32768:16384), WPK + PK_W3 + 16384,  128, 128, mode, tid, np);
    packA(wc1,                                WPK + PK_WC1,         128, 128, mode, tid, np);
    packA((const u16*)wc1 + (mode?32768:16384),WPK + PK_WC1 + 16384, 128, 128, mode, tid, np);
    packA(wc2,                                WPK + PK_WC2,         256, 128, mode, tid, np);
    packA((const u16*)wc2 + (mode?65536:32768),WPK + PK_WC2 + 32768, 256, 128, mode, tid, np);
    packA(wc3,                                WPK + PK_WC3,         32, 256, mode, tid, np);
    packA((const u16*)wc3 + (mode?16384:8192), WPK + PK_WC3 + 8192,  32, 256, mode, tid, np);
    packA(wo1, WPK + PK_WO1, 128, 256, mode, tid, np);
    packA(wo2, WPK + PK_WO2, 128, 128, mode, tid, np);
    cvtF(b_in, BIAS + OBIN, 256, mode, tid, np);
    cvtF(b1,   BIAS + OB1,  128, mode, tid, np);
    cvtF(b2,   BIAS + OB2,  256, mode, tid, np);
    cvtF(b3,   BIAS + OB3,  256, mode, tid, np);
    cvtF(bc1,  BIAS + OBC1, 256, mode, tid, np);
    cvtF(bc2,  BIAS + OBC2, 512, mode, tid, np);
    cvtF(bc3,  BIAS + OBC3, 64,  mode, tid, np);
    cvtF(bo1,  BIAS + OBO1, 128, mode, tid, np);
    cvtF(bo2,  BIAS + OBO2, 128, mode, tid, np);
    cvtF(db1,  BIAS + ODB1, 256, mode, tid, np);
    cvtF(db2,  BIAS + ODB2, 256, mode, tid, np);
    cvtF(db3,  BIAS + ODB3, 40,  mode, tid, np);
    cvtB(dw1, DWC + ODW1, 128 * 256, mode, tid, np);
    cvtB(dw2, DWC + ODW2, 256 * 256, mode, tid, np);
    cvtB(dw3, DWC + ODW3, 256 * 40,  mode, tid, np);
}

// ================= MFMA conv building blocks (64-pt tile, 4 waves) =================
// Full conv COUT=128: wave w -> co-tiles {2w,2w+1} x 4 p-tiles.
template<int CIN, int INS, int OUTS, bool NETMAX = false>
__device__ __forceinline__ void mconv128(const u16* __restrict__ wA, const float* __restrict__ bias,
                                         const u16* __restrict__ sIn, u16* __restrict__ sOut,
                                         int* __restrict__ sNet) {
    const int t = threadIdx.x;
    const int lane = t & 63, w = t >> 6, lp = lane & 15, q = lane >> 4;
    constexpr int KB = CIN / 32;
    f32x4 acc[2][4] = {};
#pragma unroll
    for (int kb = 0; kb < KB; ++kb) {
        bf16x8 a0 = *(const bf16x8*)(wA + (size_t)(((w * 2 + 0) * KB + kb) * 64 + lane) * 8);
        bf16x8 a1 = *(const bf16x8*)(wA + (size_t)(((w * 2 + 1) * KB + kb) * 64 + lane) * 8);
        bf16x8 bb[4];
#pragma unroll
        for (int pt = 0; pt < 4; ++pt)
            bb[pt] = *(const bf16x8*)(sIn + (pt * 16 + lp) * INS + kb * 32 + q * 8);
#pragma unroll
        for (int pt = 0; pt < 4; ++pt) {
            acc[0][pt] = MFMA(a0, bb[pt], acc[0][pt]);
            acc[1][pt] = MFMA(a1, bb[pt], acc[1][pt]);
        }
    }
#pragma unroll
    for (int ct = 0; ct < 2; ++ct) {
        const int co = (w * 2 + ct) * 16 + q * 4;
        f32x4 bv = *(const f32x4*)(bias + co);
#pragma unroll
        for (int pt = 0; pt < 4; ++pt) {
            f32x4 v = acc[ct][pt];
            float r0 = fmaxf(v[0] + bv[0], 0.f), r1 = fmaxf(v[1] + bv[1], 0.f);
            float r2 = fmaxf(v[2] + bv[2], 0.f), r3 = fmaxf(v[3] + bv[3], 0.f);
            if constexpr (NETMAX) {
                atomicMax(&sNet[co + 0], __float_as_int(r0));
                atomicMax(&sNet[co + 1], __float_as_int(r1));
                atomicMax(&sNet[co + 2], __float_as_int(r2));
                atomicMax(&sNet[co + 3], __float_as_int(r3));
            } else {
                const int p = pt * 16 + lp;
                *(uint2*)(sOut + p * OUTS + co) = make_uint2(pk2(r0, r1), pk2(r2, r3));
            }
        }
    }
}

// 32-out-channel chunk producer (chunk c -> sCh [p][32], stride 40), relu+bias.
// wave w -> co-tile (w&1), p-tiles {2*(w>>1), +1}
template<int CIN, int INS>
__device__ __forceinline__ void mchunk_prod(const u16* __restrict__ wA, const float* __restrict__ bias,
                                            int c, const u16* __restrict__ sIn, u16* __restrict__ sCh) {
    const int t = threadIdx.x;
    const int lane = t & 63, w = t >> 6, lp = lane & 15, q = lane >> 4;
    constexpr int KB = CIN / 32;
    const int ct = w & 1, pp = (w >> 1) * 2;
    f32x4 acc[2] = {};
#pragma unroll
    for (int kb = 0; kb < KB; ++kb) {
        bf16x8 a  = *(const bf16x8*)(wA + (size_t)(((2 * c + ct) * KB + kb) * 64 + lane) * 8);
        bf16x8 b0 = *(const bf16x8*)(sIn + ((pp + 0) * 16 + lp) * INS + kb * 32 + q * 8);
        bf16x8 b1 = *(const bf16x8*)(sIn + ((pp + 1) * 16 + lp) * INS + kb * 32 + q * 8);
        acc[0] = MFMA(a, b0, acc[0]);
        acc[1] = MFMA(a, b1, acc[1]);
    }
    const int col = ct * 16 + q * 4;
    f32x4 bv = *(const f32x4*)(bias + 32 * c + col);
#pragma unroll
    for (int i = 0; i < 2; ++i) {
        f32x4 v = acc[i];
        const int p = (pp + i) * 16 + lp;
        *(uint2*)(sCh + p * 40 + col) =
            make_uint2(pk2(fmaxf(v[0] + bv[0], 0.f), fmaxf(v[1] + bv[1], 0.f)),
                       pk2(fmaxf(v[2] + bv[2], 0.f), fmaxf(v[3] + bv[3], 0.f)));
    }
}

// chunk consumer: K=256 layer, persistent acc[CT][4]; wave co-tiles ctBase..+CT
template<int CT>
__device__ __forceinline__ void mchunk_cons(const u16* __restrict__ wA, int ctBase, int c,
                                            const u16* __restrict__ sCh, f32x4 (&acc)[CT][4]) {
    const int t = threadIdx.x;
    const int lane = t & 63, lp = lane & 15, q = lane >> 4;
    bf16x8 bb[4];
#pragma unroll
    for (int pt = 0; pt < 4; ++pt)
        bb[pt] = *(const bf16x8*)(sCh + (pt * 16 + lp) * 40 + q * 8);
#pragma unroll
    for (int k = 0; k < CT; ++k) {
        bf16x8 a = *(const bf16x8*)(wA + (size_t)(((ctBase + k) * 8 + c) * 64 + lane) * 8);
#pragma unroll
        for (int pt = 0; pt < 4; ++pt)
            acc[k][pt] = MFMA(a, bb[pt], acc[k][pt]);
    }
}

// corr consumer: wc3 (32x256); wave -> co-tile (w&1), p-tiles {2*(w>>1),+1}; acc[2] persistent
__device__ __forceinline__ void mcorr_cons(const u16* __restrict__ wA, int c,
                                           const u16* __restrict__ sCh, f32x4 (&acc)[2]) {
    const int t = threadIdx.x;
    const int lane = t & 63, w = t >> 6, lp = lane & 15, q = lane >> 4;
    const int ct = w & 1, pp = (w >> 1) * 2;
    bf16x8 a  = *(const bf16x8*)(wA + (size_t)((ct * 8 + c) * 64 + lane) * 8);
    bf16x8 b0 = *(const bf16x8*)(sCh + ((pp + 0) * 16 + lp) * 40 + q * 8);
    bf16x8 b1 = *(const bf16x8*)(sCh + ((pp + 1) * 16 + lp) * 40 + q * 8);
    acc[0] = MFMA(a, b0, acc[0]);
    acc[1] = MFMA(a, b1, acc[1]);
}

// ---------- iteration-0 fused kernel ----------
__global__ __launch_bounds__(256)
void kA0(const u16* __restrict__ featc, const int* __restrict__ clu0,
         const u16* __restrict__ WPK, const float* __restrict__ BIAS,
         u32* __restrict__ gF, int* __restrict__ gSeg) {
    __shared__ __attribute__((aligned(16))) u16 sFeat[64 * 40];
    __shared__ __attribute__((aligned(16))) u16 sCh[64 * 40];
    __shared__ __attribute__((aligned(16))) u16 sH[64 * 72];
    __shared__ __attribute__((aligned(16))) u16 sF[64 * 136];
    __shared__ __attribute__((aligned(16))) u16 sC1[64 * 136];
    __shared__ int sSeg[5120];
    __shared__ int sClu[64];
    const int t = threadIdx.x, w = t >> 6, lane = t & 63, lp = lane & 15, q = lane >> 4;
    const int b = blockIdx.y;
    const size_t bN = (size_t)b * N_;
    for (int i = t; i < 5120; i += 256) sSeg[i] = 0;

    for (int s = 0; s < 4; ++s) {
        const int n0 = (blockIdx.x * 4 + s) * 64;
        for (int i = t; i < 2560; i += 256) {
            int pt = i / 40, k = i - pt * 40;
            sFeat[i] = (k < 22) ? featc[(bN + n0 + pt) * 22 + k] : (u16)0;
        }
        if (t < 64) sClu[t] = clu0[bN + n0 + t];
        __syncthreads();
        f32x4 hacc[1][4] = {};
        for (int c = 0; c < 8; ++c) {
            mchunk_prod<32, 40>(WPK + PK_WIN, BIAS + OBIN, c, sFeat, sCh);
            __syncthreads();
            mchunk_cons<1>(WPK + PK_W1, w, c, sCh, hacc);
            __syncthreads();
        }
        {   const int co = w * 16 + q * 4;
            f32x4 bv = *(const f32x4*)(BIAS + OB1 + co);
#pragma unroll
            for (int pt = 0; pt < 4; ++pt) {
                f32x4 v = hacc[0][pt];
                int p = pt * 16 + lp;
                *(uint2*)(sH + p * 72 + co) =
                    make_uint2(pk2(fmaxf(v[0] + bv[0], 0.f), fmaxf(v[1] + bv[1], 0.f)),
                               pk2(fmaxf(v[2] + bv[2], 0.f), fmaxf(v[3] + bv[3], 0.f)));
            }
        }
        __syncthreads();
        mconv128<64, 72, 136>(WPK + PK_W2, BIAS + OB2, sH, sF, nullptr);
        __syncthreads();
        for (int i = t; i < 8192; i += 256) {
            int pt = i >> 7, ch = i & 127;
            atomicMax(&sSeg[sClu[pt] * 160 + ch], __float_as_int(b2f(sF[pt * 136 + ch])));
        }
        for (int i = t; i < 4096; i += 256) {
            int pt = i >> 6, c2 = i & 63;
            gF[(bN + n0 + pt) * 64 + c2] =
                (u32)sF[pt * 136 + c2 * 2] | ((u32)sF[pt * 136 + c2 * 2 + 1] << 16);
        }
        mconv128<128, 136, 136>(WPK + PK_WC1, BIAS + OBC1, sF, sC1, nullptr);
        __syncthreads();
        f32x4 cacc[2] = {};
        for (int c = 0; c < 8; ++c) {
            mchunk_prod<128, 136>(WPK + PK_WC2, BIAS + OBC2, c, sC1, sCh);
            __syncthreads();
            mcorr_cons(WPK + PK_WC3, c, sCh, cacc);
            __syncthreads();
        }
        {   const int col = (w & 1) * 16 + q * 4, pp = (w >> 1) * 2;
            f32x4 bv = *(const f32x4*)(BIAS + OBC3 + col);
#pragma unroll
            for (int i = 0; i < 2; ++i) {
                int p = (pp + i) * 16 + lp;
                int cl = sClu[p];
                f32x4 v = cacc[i];
                atomicMax(&sSeg[cl * 160 + 128 + col + 0], __float_as_int(fmaxf(v[0] + bv[0], 0.f)));
                atomicMax(&sSeg[cl * 160 + 128 + col + 1], __float_as_int(fmaxf(v[1] + bv[1], 0.f)));
                atomicMax(&sSeg[cl * 160 + 128 + col + 2], __float_as_int(fmaxf(v[2] + bv[2], 0.f)));
                atomicMax(&sSeg[cl * 160 + 128 + col + 3], __float_as_int(fmaxf(v[3] + bv[3], 0.f)));
            }
        }
        __syncthreads();
    }
    for (int i = t; i < 5120; i += 256) atomicMax(&gSeg[b * 5120 + i], sSeg[i]);
}

// ---------- per-batch cluster math: cf2[b][c][ch] ----------
__global__ __launch_bounds__(256)
void kB(const int* __restrict__ gSeg, float* __restrict__ cf2) {
    __shared__ float sA[5120];
    __shared__ float sR[1024];
    __shared__ float sI[32];
    const int t = threadIdx.x, b = blockIdx.x;
    for (int i = t; i < 5120; i += 256) sA[i] = __int_as_float(gSeg[b * 5120 + i]);
    __syncthreads();
    if (t < 32) {
        float s = 0.f;
        for (int j = 0; j < 32; ++j) { float v = sA[t * 160 + 128 + j]; s = fmaf(v, v, s); }
        sI[t] = 1.f / fmaxf(sqrtf(s), 1e-12f);
    }
    __syncthreads();
    for (int i = t; i < 1024; i += 256) {
        int ca = i >> 5, cb = i & 31;
        float s = 0.f;
        for (int j = 0; j < 32; ++j)
            s = fmaf(sA[ca * 160 + 128 + j], sA[cb * 160 + 128 + j], s);
        sR[i] = s * sI[ca] * sI[cb];
    }
    __syncthreads();
    for (int i = t; i < 4096; i += 256) {
        int c = i >> 7, ch = i & 127;
        float s = 0.f;
        for (int cp = 0; cp < 32; ++cp)
            s = fmaf(sA[cp * 160 + ch], sR[cp * 32 + c], s);
        cf2[((size_t)b * 32 + c) * 128 + ch] = s;
    }
}

// ---------- iteration-1 fused kernel ----------
__global__ __launch_bounds__(256)
void kA1(const u32* __restrict__ gFp, const int* __restrict__ clu_g,
         const int* __restrict__ clu_s, const float* __restrict__ cf2,
         const u16* __restrict__ WPK, const float* __restrict__ BIAS,
         u32* __restrict__ gFo, int* __restrict__ gSeg) {
    __shared__ __attribute__((aligned(16))) u16 sIC[64 * 136];   // f128_in, later c1
    __shared__ __attribute__((aligned(16))) u16 sCh[64 * 40];
    __shared__ __attribute__((aligned(16))) u16 sH[64 * 72];
    __shared__ __attribute__((aligned(16))) u16 sF[64 * 136];
    __shared__ int sSeg[5120];
    __shared__ int sClu0[64];
    __shared__ int sClu1[64];
    const int t = threadIdx.x, w = t >> 6, lane = t & 63, lp = lane & 15, q = lane >> 4;
    const int b = blockIdx.y;
    const size_t bN = (size_t)b * N_;
    for (int i = t; i < 5120; i += 256) sSeg[i] = 0;

    for (int s = 0; s < 4; ++s) {
        const int n0 = (blockIdx.x * 4 + s) * 64;
        for (int i = t; i < 4096; i += 256) {
            int pt = i >> 6, c2 = i & 63;
            u32 v = gFp[(bN + n0 + pt) * 64 + c2];
            sIC[pt * 136 + c2 * 2]     = (u16)v;
            sIC[pt * 136 + c2 * 2 + 1] = (u16)(v >> 16);
        }
        if (t < 64) sClu0[t] = clu_g[bN + n0 + t];
        else if (t < 128) sClu1[t - 64] = clu_s[bN + n0 + (t - 64)];
        __syncthreads();
        f32x4 hacc[1][4] = {};
        for (int c = 0; c < 8; ++c) {
            if (c < 4) {
                mchunk_prod<128, 136>(WPK + PK_W3, BIAS + OB3, c, sIC, sCh);
            } else {
                for (int i = t; i < 2048; i += 256) {
                    int pt = i >> 5, m = i & 31;
                    sCh[pt * 40 + m] =
                        f2b(cf2[((size_t)b * 32 + sClu0[pt]) * 128 + (c - 4) * 32 + m]);
                }
            }
            __syncthreads();
            mchunk_cons<1>(WPK + PK_W1 + 16384, w, c, sCh, hacc);
            __syncthreads();
        }
        {   const int co = w * 16 + q * 4;
            f32x4 bv = *(const f32x4*)(BIAS + OB1 + 64 + co);
#pragma unroll
            for (int pt = 0; pt < 4; ++pt) {
                f32x4 v = hacc[0][pt];
                int p = pt * 16 + lp;
                *(uint2*)(sH + p * 72 + co) =
                    make_uint2(pk2(fmaxf(v[0] + bv[0], 0.f), fmaxf(v[1] + bv[1], 0.f)),
                               pk2(fmaxf(v[2] + bv[2], 0.f), fmaxf(v[3] + bv[3], 0.f)));
            }
        }
        __syncthreads();
        mconv128<64, 72, 136>(WPK + PK_W2 + 8192, BIAS + OB2 + 128, sH, sF, nullptr);
        __syncthreads();
        for (int i = t; i < 8192; i += 256) {
            int pt = i >> 7, ch = i & 127;
            atomicMax(&sSeg[sClu1[pt] * 160 + ch], __float_as_int(b2f(sF[pt * 136 + ch])));
        }
        for (int i = t; i < 4096; i += 256) {
            int pt = i >> 6, c2 = i & 63;
            gFo[(bN + n0 + pt) * 64 + c2] =
                (u32)sF[pt * 136 + c2 * 2] | ((u32)sF[pt * 136 + c2 * 2 + 1] << 16);
        }
        mconv128<128, 136, 136>(WPK + PK_WC1 + 16384, BIAS + OBC1 + 128, sF, sIC, nullptr);
        __syncthreads();
        f32x4 cacc[2] = {};
        for (int c = 0; c < 8; ++c) {
            mchunk_prod<128, 136>(WPK + PK_WC2 + 32768, BIAS + OBC2 + 256, c, sIC, sCh);
            __syncthreads();
            mcorr_cons(WPK + PK_WC3 + 8192, c, sCh, cacc);
            __syncthreads();
        }
        {   const int col = (w & 1) * 16 + q * 4, pp = (w >> 1) * 2;
            f32x4 bv = *(const f32x4*)(BIAS + OBC3 + 32 + col);
#pragma unroll
            for (int i = 0; i < 2; ++i) {
                int p = (pp + i) * 16 + lp;
                int cl = sClu1[p];
                f32x4 v = cacc[i];
                atomicMax(&sSeg[cl * 160 + 128 + col + 0], __float_as_int(fmaxf(v[0] + bv[0], 0.f)));
                atomicMax(&sSeg[cl * 160 + 128 + col + 1], __float_as_int(fmaxf(v[1] + bv[1], 0.f)));
                atomicMax(&sSeg[cl * 160 + 128 + col + 2], __float_as_int(fmaxf(v[2] + bv[2], 0.f)));
                atomicMax(&sSeg[cl * 160 + 128 + col + 3], __float_as_int(fmaxf(v[3] + bv[3], 0.f)));
            }
        }
        __syncthreads();
    }
    for (int i = t; i < 5120; i += 256) atomicMax(&gSeg[b * 5120 + i], sSeg[i]);
}

// ---------- final conv head + per-channel max over points ----------
__global__ __launch_bounds__(256)
void kC(const u32* __restrict__ gFp, const int* __restrict__ clu_g,
        const float* __restrict__ cf2,
        const u16* __restrict__ WPK, const float* __restrict__ BIAS,
        int* __restrict__ gNet) {
    __shared__ __attribute__((aligned(16))) u16 sIO[64 * 136];   // f128_in, later o1
    __shared__ __attribute__((aligned(16))) u16 sCh[64 * 40];
    __shared__ int sNet[128];
    __shared__ int sClu[64];
    const int t = threadIdx.x, w = t >> 6, lane = t & 63, lp = lane & 15, q = lane >> 4;
    const int b = blockIdx.y;
    const size_t bN = (size_t)b * N_;
    if (t < 128) sNet[t] = 0;

    for (int s = 0; s < 2; ++s) {
        const int n0 = (blockIdx.x * 2 + s) * 64;
        for (int i = t; i < 4096; i += 256) {
            int pt = i >> 6, c2 = i & 63;
            u32 v = gFp[(bN + n0 + pt) * 64 + c2];
            sIO[pt * 136 + c2 * 2]     = (u16)v;
            sIO[pt * 136 + c2 * 2 + 1] = (u16)(v >> 16);
        }
        if (t < 64) sClu[t] = clu_g[bN + n0 + t];
        __syncthreads();
        f32x4 oacc[2][4] = {};
        for (int c = 0; c < 8; ++c) {
            if (c < 4) {
                mchunk_prod<128, 136>(WPK + PK_W3 + 16384, BIAS + OB3 + 128, c, sIO, sCh);
            } else {
                for (int i = t; i < 2048; i += 256) {
                    int pt = i >> 5, m = i & 31;
                    sCh[pt * 40 + m] =
                        f2b(cf2[((size_t)b * 32 + sClu[pt]) * 128 + (c - 4) * 32 + m]);
                }
            }
            __syncthreads();
            mchunk_cons<2>(WPK + PK_WO1, 2 * w, c, sCh, oacc);
            __syncthreads();
        }
#pragma unroll
        for (int ct = 0; ct < 2; ++ct) {
            const int co = (2 * w + ct) * 16 + q * 4;
            f32x4 bv = *(const f32x4*)(BIAS + OBO1 + co);
#pragma unroll
            for (int pt = 0; pt < 4; ++pt) {
                f32x4 v = oacc[ct][pt];
                int p = pt * 16 + lp;
                *(uint2*)(sIO + p * 136 + co) =
                    make_uint2(pk2(fmaxf(v[0] + bv[0], 0.f), fmaxf(v[1] + bv[1], 0.f)),
                               pk2(fmaxf(v[2] + bv[2], 0.f), fmaxf(v[3] + bv[3], 0.f)));
            }
        }
        __syncthreads();
        mconv128<128, 136, 136, true>(WPK + PK_WO2, BIAS + OBO2, sIO, nullptr, sNet);
        __syncthreads();
    }
    if (t < 128) atomicMax(&gNet[b * 128 + t], sNet[t]);
}

// ---------- tiny MLP head (dual-mode output) ----------
__global__ __launch_bounds__(256)
void kD(const int* __restrict__ gNet, const u16* __restrict__ DWC,
        const float* __restrict__ BIAS, void* __restrict__ outv,
        const int* __restrict__ modep) {
    __shared__ float sN[1024];
    __shared__ float sD1[2048];
    __shared__ float sD2[2048];
    const int mode = *modep;
    const int t = threadIdx.x;
    for (int i = t; i < 1024; i += 256) sN[i] = __int_as_float(gNet[i]);
    __syncthreads();
    for (int i = t; i < 2048; i += 256) {
        int bb = i >> 8, o = i & 255;
        float s = BIAS[ODB1 + o];
        for (int k = 0; k < 128; ++k)
            s = fmaf(sN[bb * 128 + k], b2f(DWC[ODW1 + k * 256 + o]), s);
        sD1[i] = (s >= 0.f) ? s : 0.2f * s;
    }
    __syncthreads();
    for (int i = t; i < 2048; i += 256) {
        int bb = i >> 8, o = i & 255;
        float s = BIAS[ODB2 + o];
        for (int k = 0; k < 256; ++k)
            s = fmaf(sD1[bb * 256 + k], b2f(DWC[ODW2 + k * 256 + o]), s);
        sD2[i] = (s >= 0.f) ? s : 0.2f * s;
    }
    __syncthreads();
    for (int i = t; i < 320; i += 256) {
        int bb = i / 40, o = i - bb * 40;
        float s = BIAS[ODB3 + o];
        for (int k = 0; k < 256; ++k)
            s = fmaf(sD2[bb * 256 + k], b2f(DWC[ODW3 + k * 40 + o]), s);
        if (mode) ((float*)outv)[i] = s;
        else      ((u16*)outv)[i]   = f2b(s);
    }
}

extern "C" void kernel_launch(void* const* d_in, const int* in_sizes, int n_in,
                              void* d_out, int out_size, void* d_ws, size_t ws_size,
                              hipStream_t stream) {
    const void* feat = d_in[0];
    const int* clus = (const int*)d_in[1];

    char* ws = (char*)d_ws;
    u16*   WPK   = (u16*)(ws + OFS_WPK);
    float* BIAS  = (float*)(ws + OFS_BIAS);
    u16*   DWC   = (u16*)(ws + OFS_DWC);
    int*   modep = (int*)(ws + OFS_MODE);
    u16*   FEATC = (u16*)(ws + OFS_FEATC);
    int*   seg0  = (int*)(ws + OFS_GACC0);
    int*   seg1  = (int*)(ws + OFS_GACC1);
    int*   gNet  = (int*)(ws + OFS_GNET);
    float* cf20  = (float*)(ws + OFS_CF20);
    float* cf21  = (float*)(ws + OFS_CF21);
    u32*   f0    = (u32*)(ws + OFS_F0);
    u32*   f1    = (u32*)(ws + OFS_F1);

    hipMemsetAsync(ws + OFS_GACC0, 0, GACC_ZERO_BYTES, stream);
    hipLaunchKernelGGL(kSniff, dim3(1), dim3(256), 0, stream, (const u16*)feat, modep);
    hipLaunchKernelGGL(kPrep, dim3(256), dim3(256), 0, stream,
                       feat, d_in[2], d_in[3], d_in[4], d_in[5], d_in[6], d_in[7],
                       d_in[8], d_in[9], d_in[10], d_in[11], d_in[12], d_in[13],
                       d_in[14], d_in[15], d_in[16], d_in[17], d_in[18], d_in[19],
                       d_in[20], d_in[21], d_in[22], d_in[23], d_in[24], d_in[25],
                       WPK, BIAS, DWC, FEATC, modep);

    const int* clu0 = clus;
    const int* clu1 = clus + (size_t)B_ * N_;
    dim3 blk(256);

    hipLaunchKernelGGL(kA0, dim3(128, 8), blk, 0, stream,
                       FEATC, clu0, WPK, BIAS, f0, seg0);
    hipLaunchKernelGGL(kB, dim3(8), blk, 0, stream, seg0, cf20);
    hipLaunchKernelGGL(kA1, dim3(128, 8), blk, 0, stream,
                       f0, clu0, clu1, cf20, WPK, BIAS, f1, seg1);
    hipLaunchKernelGGL(kB, dim3(8), blk, 0, stream, seg1, cf21);
    hipLaunchKernelGGL(kC, dim3(256, 8), blk, 0, stream,
                       f1, clu1, cf21, WPK, BIAS, gNet);
    hipLaunchKernelGGL(kD, dim3(1), blk, 0, stream,
                       gNet, DWC, BIAS, d_out, modep);
}